// Round 6
// baseline (10329.808 us; speedup 1.0000x reference)
//
#include <hip/hip_runtime.h>
#include <math.h>

#define HH   1080
#define WW   1920
#define NPIX (HH*WW)          // 2073600
#define MAXP 2048
#define NBLK 256
#define NTHR 512
#define NWAVE (NTHR/64)       // 8
#define TOTTHR (NBLK*NTHR)    // 131072 = 2^17
#define KPT  16               // 131072*16 = 2097152 >= NPIX

#define CXF 960.0f
#define CYF 540.0f
#define FXF 1050.0f
#define FYF 1050.0f

// per-iteration, per-block communication slots (zeroed each call by zero_ws_kernel)
__device__ unsigned long long g_packed[MAXP * NBLK];  // 4 MB  (dist_bits<<32 | ~idx), 0 = sentinel
__device__ float              g_z[MAXP * NBLK];       // 2 MB  candidate depth, 0.0f = sentinel

__device__ __forceinline__ float proj_x(float u, float d) {
    return __fdiv_rn(__fmul_rn(__fsub_rn(u, CXF), d), FXF);
}
__device__ __forceinline__ float proj_y(float v, float d) {
    return __fdiv_rn(__fmul_rn(__fsub_rn(v, CYF), d), FYF);
}
__device__ __forceinline__ unsigned long long umax64(unsigned long long a, unsigned long long b) {
    return a > b ? a : b;
}

__global__ void zero_ws_kernel() {
    unsigned i = blockIdx.x * 256u + threadIdx.x;
    if (i < MAXP * NBLK) { g_packed[i] = 0ull; g_z[i] = 0.0f; }
}

// ---- register point storage: named scalars via macro expansion ----
#define FOR16(M)  M(0) M(1) M(2) M(3) M(4) M(5) M(6) M(7) M(8) M(9) M(10) M(11) M(12) M(13) M(14) M(15)
#define FOR16D(M) M(15) M(14) M(13) M(12) M(11) M(10) M(9) M(8) M(7) M(6) M(5) M(4) M(3) M(2) M(1) M(0)

#define DECLJ(j) float X##j, Y##j, Z##j, D##j;

#define INITJ(j) { \
    unsigned idx = tid + j##u * (unsigned)TOTTHR; \
    if (idx < NPIX) { \
        float d = depth[idx]; \
        float u = (float)(idx % WW); \
        float v = (float)(idx / WW); \
        bool val = (d > 0.1f) && (d < 2.0f) && __builtin_isfinite(d); \
        X##j = val ? proj_x(u, d) : FINF; \
        Y##j = val ? proj_y(v, d) : FINF; \
        Z##j = val ? d : FINF; \
        D##j = FINF; \
    } else { X##j = 0.f; Y##j = 0.f; Z##j = 0.f; D##j = -1.0f; } }

// descending j + ">=" keeps the LOWEST index on distance ties (np.argmax semantics)
#define UPDJ(j) { \
    float dx = __fsub_rn(X##j, px); \
    float dy = __fsub_rn(Y##j, py); \
    float dz = __fsub_rn(Z##j, pz); \
    float s  = __fadd_rn(__fadd_rn(__fmul_rn(dx, dx), __fmul_rn(dy, dy)), __fmul_rn(dz, dz)); \
    float nd = fminf(D##j, s); \
    D##j = nd; \
    if (nd >= bestd) { bestd = nd; besti = tid + j##u * (unsigned)TOTTHR; bestz = Z##j; } }

__global__ __attribute__((amdgpu_flat_work_group_size(NTHR, NTHR), amdgpu_waves_per_eu(1, 2)))
void fps_kernel(const float* __restrict__ depth, const float* __restrict__ rgb,
                float* __restrict__ out)
{
    const unsigned tid  = blockIdx.x * NTHR + threadIdx.x;
    const unsigned lane = threadIdx.x & 63u;
    const unsigned wid  = threadIdx.x >> 6;
    const unsigned blk  = blockIdx.x;
    const float FINF = __int_as_float(0x7f800000);

    __shared__ unsigned long long s_pp[NWAVE];
    __shared__ float              s_pz[NWAVE];
    __shared__ unsigned long long s_gp[4];
    __shared__ float              s_d[NBLK];
    __shared__ unsigned           s_widx[MAXP];   // block 0 only: selected indices

    FOR16(DECLJ)
    FOR16(INITJ)

    if (threadIdx.x == 0) s_widx[0] = 0u;

    // first FPS point = flat index 0
    float px, py, pz;
    {
        float d = depth[0];
        bool val = (d > 0.1f) && (d < 2.0f) && __builtin_isfinite(d);
        px = val ? proj_x(0.0f, d) : FINF;
        py = val ? proj_y(0.0f, d) : FINF;
        pz = val ? d : FINF;
    }

    for (int it = 1; it < MAXP; ++it) {
        // ---- register distance update + thread-local argmax ----
        float bestd = -2.0f, bestz = 0.0f;
        unsigned besti = 0u;
        FOR16D(UPDJ)

        unsigned long long pk =
            ((unsigned long long)__float_as_uint(bestd) << 32) |
            (unsigned long long)(~besti);
        float zz = bestz;

        // ---- wave reduce (max on packed, carry z) ----
        #pragma unroll
        for (int off = 32; off; off >>= 1) {
            unsigned long long o  = __shfl_xor(pk, off);
            float              oz = __shfl_xor(zz, off);
            if (o > pk) { pk = o; zz = oz; }
        }
        if (lane == 0) { s_pp[wid] = pk; s_pz[wid] = zz; }
        __syncthreads();

        // ---- wave 0: block reduce + relaxed write-through stores (no fences) ----
        if (wid == 0) {
            unsigned long long p2 = s_pp[lane & 7u];
            float              z2 = s_pz[lane & 7u];
            #pragma unroll
            for (int off = 4; off; off >>= 1) {
                unsigned long long o  = __shfl_xor(p2, off);
                float              oz = __shfl_xor(z2, off);
                if (o > p2) { p2 = o; z2 = oz; }
            }
            if (lane == 0) {
                __hip_atomic_store(&g_z[(size_t)it * NBLK + blk], z2,
                                   __ATOMIC_RELAXED, __HIP_MEMORY_SCOPE_AGENT);
                __hip_atomic_store(&g_packed[(size_t)it * NBLK + blk], p2,
                                   __ATOMIC_RELAXED, __HIP_MEMORY_SCOPE_AGENT);
            }
        }

        // ---- one concurrent poll round: waves 0-3 poll packed, waves 4-7 poll z ----
        if (wid < 4) {
            const unsigned long long* ap = &g_packed[(size_t)it * NBLK + wid * 64u + lane];
            unsigned long long v;
            for (;;) {
                v = __hip_atomic_load(ap, __ATOMIC_RELAXED, __HIP_MEMORY_SCOPE_AGENT);
                if (v != 0ull) break;
                __builtin_amdgcn_s_sleep(1);
            }
            #pragma unroll
            for (int off = 32; off; off >>= 1) v = umax64(v, __shfl_xor(v, off));
            if (lane == 0) s_gp[wid] = v;
        } else {
            unsigned slot = (wid - 4u) * 64u + lane;
            const float* ad = &g_z[(size_t)it * NBLK + slot];
            float zv;
            for (;;) {
                zv = __hip_atomic_load(ad, __ATOMIC_RELAXED, __HIP_MEMORY_SCOPE_AGENT);
                if (zv != 0.0f) break;
                __builtin_amdgcn_s_sleep(1);
            }
            s_d[slot] = zv;
        }
        __syncthreads();

        // ---- everyone computes the winner locally; reconstruct its xyz ----
        unsigned long long w = umax64(umax64(s_gp[0], s_gp[1]), umax64(s_gp[2], s_gp[3]));
        unsigned widx = ~((unsigned)(w & 0xFFFFFFFFull));
        unsigned wblk = (widx & (unsigned)(TOTTHR - 1)) / NTHR;  // owner block
        float    wd   = s_d[wblk];
        if (blk == 0 && threadIdx.x == 0) s_widx[it] = widx;

        float uu = (float)(widx % WW);
        float vv = (float)(widx / WW);
        bool val = (wd > 0.1f) && (wd < 2.0f) && __builtin_isfinite(wd);
        px = val ? proj_x(uu, wd) : FINF;
        py = val ? proj_y(vv, wd) : FINF;
        pz = val ? wd : FINF;
    }

    // ---- epilogue: block 0 gathers, normalizes, writes [2048,9] ----
    if (blk == 0) {
        __syncthreads();
        float ex[4], ey[4], ez[4], er[4], eg[4], eb[4];
        #pragma unroll
        for (int q = 0; q < 4; ++q) {
            int i = (int)threadIdx.x + q * NTHR;
            unsigned sidx = s_widx[i];
            float d = depth[sidx];
            float u = (float)(sidx % WW);
            float v = (float)(sidx / WW);
            bool val = (d > 0.1f) && (d < 2.0f) && __builtin_isfinite(d);
            ex[q] = val ? proj_x(u, d) : FINF;
            ey[q] = val ? proj_y(v, d) : FINF;
            ez[q] = val ? d : FINF;
            er[q] = val ? __fdiv_rn(rgb[3u * sidx + 0u], 255.0f) : 0.0f;
            eg[q] = val ? __fdiv_rn(rgb[3u * sidx + 1u], 255.0f) : 0.0f;
            eb[q] = val ? __fdiv_rn(rgb[3u * sidx + 2u], 255.0f) : 0.0f;
        }
        float mn[3], mx[3];
        mn[0] = fminf(fminf(ex[0], ex[1]), fminf(ex[2], ex[3]));
        mx[0] = fmaxf(fmaxf(ex[0], ex[1]), fmaxf(ex[2], ex[3]));
        mn[1] = fminf(fminf(ey[0], ey[1]), fminf(ey[2], ey[3]));
        mx[1] = fmaxf(fmaxf(ey[0], ey[1]), fmaxf(ey[2], ey[3]));
        mn[2] = fminf(fminf(ez[0], ez[1]), fminf(ez[2], ez[3]));
        mx[2] = fmaxf(fmaxf(ez[0], ez[1]), fmaxf(ez[2], ez[3]));
        #pragma unroll
        for (int c = 0; c < 3; ++c) {
            for (int off = 32; off > 0; off >>= 1) {
                mn[c] = fminf(mn[c], __shfl_xor(mn[c], off));
                mx[c] = fmaxf(mx[c], __shfl_xor(mx[c], off));
            }
        }
        __shared__ float s_mn[NWAVE][3], s_mx[NWAVE][3];
        __shared__ float f_mn[3], f_sc[3];
        if (lane == 0) {
            for (int c = 0; c < 3; ++c) { s_mn[wid][c] = mn[c]; s_mx[wid][c] = mx[c]; }
        }
        __syncthreads();
        if (wid == 0) {
            float a[3], b[3];
            for (int c = 0; c < 3; ++c) {
                a[c] = (lane < NWAVE) ? s_mn[lane][c] : FINF;
                b[c] = (lane < NWAVE) ? s_mx[lane][c] : -FINF;
            }
            for (int off = NWAVE / 2; off > 0; off >>= 1) {
                for (int c = 0; c < 3; ++c) {
                    a[c] = fminf(a[c], __shfl_xor(a[c], off));
                    b[c] = fmaxf(b[c], __shfl_xor(b[c], off));
                }
            }
            if (lane == 0) {
                for (int c = 0; c < 3; ++c) {
                    f_mn[c] = a[c];
                    float m = __fsub_rn(b[c], a[c]);   // == max(centered) by monotonicity
                    f_sc[c] = (m < 1e-8f) ? 1.0f : m;
                }
            }
        }
        __syncthreads();
        float MN0 = f_mn[0], MN1 = f_mn[1], MN2 = f_mn[2];
        float SC0 = f_sc[0], SC1 = f_sc[1], SC2 = f_sc[2];
        #pragma unroll
        for (int q = 0; q < 4; ++q) {
            int i = (int)threadIdx.x + q * NTHR;
            out[9 * i + 0] = ex[q];
            out[9 * i + 1] = ey[q];
            out[9 * i + 2] = ez[q];
            out[9 * i + 3] = er[q];
            out[9 * i + 4] = eg[q];
            out[9 * i + 5] = eb[q];
            out[9 * i + 6] = __fdiv_rn(__fsub_rn(ex[q], MN0), SC0);
            out[9 * i + 7] = __fdiv_rn(__fsub_rn(ey[q], MN1), SC1);
            out[9 * i + 8] = __fdiv_rn(__fsub_rn(ez[q], MN2), SC2);
        }
    }
}

extern "C" void kernel_launch(void* const* d_in, const int* in_sizes, int n_in,
                              void* d_out, int out_size, void* d_ws, size_t ws_size,
                              hipStream_t stream) {
    const float* depth = (const float*)d_in[0];
    const float* rgb   = (const float*)d_in[1];
    float* out = (float*)d_out;

    // re-initialize communication slots (deterministic per call / per graph replay)
    zero_ws_kernel<<<dim3((MAXP * NBLK + 255) / 256), dim3(256), 0, stream>>>();

    void* args[] = { (void*)&depth, (void*)&rgb, (void*)&out };
    hipLaunchCooperativeKernel((const void*)fps_kernel, dim3(NBLK), dim3(NTHR),
                               args, 0, stream);
}

// Round 7
// 10311.369 us; speedup vs baseline: 1.0018x; 1.0018x over previous
//
#include <hip/hip_runtime.h>
#include <math.h>

#define HH   1080
#define WW   1920
#define NPIX (HH*WW)          // 2073600
#define MAXP 2048
#define NBLK 256
#define NTHR 512
#define NWAVE (NTHR/64)       // 8
#define TOTTHR (NBLK*NTHR)    // 131072 = 2^17
#define KPT  16               // 131072*16 = 2097152 >= NPIX

#define CXF 960.0f
#define CYF 540.0f
#define FXF 1050.0f
#define FYF 1050.0f

// per-iteration, per-block communication slots (zeroed each call by zero_ws_kernel)
__device__ unsigned long long g_packed[MAXP * NBLK];  // 4 MB  (dist_bits<<32 | ~idx), 0 = sentinel
__device__ float              g_z[MAXP * NBLK];       // 2 MB  candidate depth, 0.0f = sentinel

__device__ __forceinline__ float proj_x(float u, float d) {
    return __fdiv_rn(__fmul_rn(__fsub_rn(u, CXF), d), FXF);
}
__device__ __forceinline__ float proj_y(float v, float d) {
    return __fdiv_rn(__fmul_rn(__fsub_rn(v, CYF), d), FYF);
}
__device__ __forceinline__ unsigned long long umax64(unsigned long long a, unsigned long long b) {
    return a > b ? a : b;
}

__global__ void zero_ws_kernel() {
    unsigned i = blockIdx.x * 256u + threadIdx.x;
    if (i < MAXP * NBLK) { g_packed[i] = 0ull; g_z[i] = 0.0f; }
}

// ---- register point storage: named scalars via macro expansion ----
#define FOR16(M)  M(0) M(1) M(2) M(3) M(4) M(5) M(6) M(7) M(8) M(9) M(10) M(11) M(12) M(13) M(14) M(15)
#define FOR16D(M) M(15) M(14) M(13) M(12) M(11) M(10) M(9) M(8) M(7) M(6) M(5) M(4) M(3) M(2) M(1) M(0)

#define DECLJ(j) float X##j, Y##j, Z##j, D##j;

#define INITJ(j) { \
    unsigned idx = tid + j##u * (unsigned)TOTTHR; \
    if (idx < NPIX) { \
        float d = depth[idx]; \
        float u = (float)(idx % WW); \
        float v = (float)(idx / WW); \
        bool val = (d > 0.1f) && (d < 2.0f) && __builtin_isfinite(d); \
        X##j = val ? proj_x(u, d) : FINF; \
        Y##j = val ? proj_y(v, d) : FINF; \
        Z##j = val ? d : FINF; \
        D##j = FINF; \
    } else { X##j = 0.f; Y##j = 0.f; Z##j = 0.f; D##j = -1.0f; } }

// pin state into VGPRs: opaque asm outputs cannot be rematerialized or sunk
// into the loop (prevents the compiler from re-loading depth + redoing the
// projection divides every iteration — the round-2..6 VGPR=56 pathology)
#define PINJ(j) asm volatile("" : "+v"(X##j), "+v"(Y##j), "+v"(Z##j), "+v"(D##j));

// descending j + ">=" keeps the LOWEST index on distance ties (np.argmax semantics)
#define UPDJ(j) { \
    float dx = __fsub_rn(X##j, px); \
    float dy = __fsub_rn(Y##j, py); \
    float dz = __fsub_rn(Z##j, pz); \
    float s  = __fadd_rn(__fadd_rn(__fmul_rn(dx, dx), __fmul_rn(dy, dy)), __fmul_rn(dz, dz)); \
    float nd = fminf(D##j, s); \
    D##j = nd; \
    if (nd >= bestd) { bestd = nd; besti = tid + j##u * (unsigned)TOTTHR; bestz = Z##j; } }

__global__ __attribute__((amdgpu_flat_work_group_size(NTHR, NTHR), amdgpu_waves_per_eu(1, 2)))
void fps_kernel(const float* __restrict__ depth, const float* __restrict__ rgb,
                float* __restrict__ out)
{
    const unsigned tid  = blockIdx.x * NTHR + threadIdx.x;
    const unsigned lane = threadIdx.x & 63u;
    const unsigned wid  = threadIdx.x >> 6;
    const unsigned blk  = blockIdx.x;
    const float FINF = __int_as_float(0x7f800000);

    __shared__ unsigned long long s_pp[NWAVE];
    __shared__ float              s_pz[NWAVE];
    __shared__ unsigned long long s_gp[4];
    __shared__ float              s_d[NBLK];
    __shared__ unsigned           s_widx[MAXP];   // block 0 only: selected indices

    FOR16(DECLJ)
    FOR16(INITJ)
    FOR16(PINJ)

    if (threadIdx.x == 0) s_widx[0] = 0u;

    // first FPS point = flat index 0
    float px, py, pz;
    {
        float d = depth[0];
        bool val = (d > 0.1f) && (d < 2.0f) && __builtin_isfinite(d);
        px = val ? proj_x(0.0f, d) : FINF;
        py = val ? proj_y(0.0f, d) : FINF;
        pz = val ? d : FINF;
    }

    for (int it = 1; it < MAXP; ++it) {
        // ---- register distance update + thread-local argmax ----
        float bestd = -2.0f, bestz = 0.0f;
        unsigned besti = 0u;
        FOR16D(UPDJ)

        unsigned long long pk =
            ((unsigned long long)__float_as_uint(bestd) << 32) |
            (unsigned long long)(~besti);
        float zz = bestz;

        // ---- wave reduce (max on packed, carry z) ----
        #pragma unroll
        for (int off = 32; off; off >>= 1) {
            unsigned long long o  = __shfl_xor(pk, off);
            float              oz = __shfl_xor(zz, off);
            if (o > pk) { pk = o; zz = oz; }
        }
        if (lane == 0) { s_pp[wid] = pk; s_pz[wid] = zz; }
        __syncthreads();

        // ---- wave 0: block reduce + relaxed write-through stores (no fences) ----
        if (wid == 0) {
            unsigned long long p2 = s_pp[lane & 7u];
            float              z2 = s_pz[lane & 7u];
            #pragma unroll
            for (int off = 4; off; off >>= 1) {
                unsigned long long o  = __shfl_xor(p2, off);
                float              oz = __shfl_xor(z2, off);
                if (o > p2) { p2 = o; z2 = oz; }
            }
            if (lane == 0) {
                __hip_atomic_store(&g_z[(size_t)it * NBLK + blk], z2,
                                   __ATOMIC_RELAXED, __HIP_MEMORY_SCOPE_AGENT);
                __hip_atomic_store(&g_packed[(size_t)it * NBLK + blk], p2,
                                   __ATOMIC_RELAXED, __HIP_MEMORY_SCOPE_AGENT);
            }
        }

        // ---- one concurrent poll round: waves 0-3 poll packed, waves 4-7 poll z ----
        if (wid < 4) {
            const unsigned long long* ap = &g_packed[(size_t)it * NBLK + wid * 64u + lane];
            unsigned long long v;
            for (;;) {
                v = __hip_atomic_load(ap, __ATOMIC_RELAXED, __HIP_MEMORY_SCOPE_AGENT);
                if (v != 0ull) break;
                __builtin_amdgcn_s_sleep(1);
            }
            #pragma unroll
            for (int off = 32; off; off >>= 1) v = umax64(v, __shfl_xor(v, off));
            if (lane == 0) s_gp[wid] = v;
        } else {
            unsigned slot = (wid - 4u) * 64u + lane;
            const float* ad = &g_z[(size_t)it * NBLK + slot];
            float zv;
            for (;;) {
                zv = __hip_atomic_load(ad, __ATOMIC_RELAXED, __HIP_MEMORY_SCOPE_AGENT);
                if (zv != 0.0f) break;
                __builtin_amdgcn_s_sleep(1);
            }
            s_d[slot] = zv;
        }
        __syncthreads();

        // ---- everyone computes the winner locally; reconstruct its xyz ----
        unsigned long long w = umax64(umax64(s_gp[0], s_gp[1]), umax64(s_gp[2], s_gp[3]));
        unsigned widx = ~((unsigned)(w & 0xFFFFFFFFull));
        unsigned wblk = (widx & (unsigned)(TOTTHR - 1)) / NTHR;  // owner block
        float    wd   = s_d[wblk];
        if (blk == 0 && threadIdx.x == 0) s_widx[it] = widx;

        float uu = (float)(widx % WW);
        float vv = (float)(widx / WW);
        bool val = (wd > 0.1f) && (wd < 2.0f) && __builtin_isfinite(wd);
        px = val ? proj_x(uu, wd) : FINF;
        py = val ? proj_y(vv, wd) : FINF;
        pz = val ? wd : FINF;
    }

    // ---- epilogue: block 0 gathers, normalizes, writes [2048,9] ----
    if (blk == 0) {
        __syncthreads();
        float ex[4], ey[4], ez[4], er[4], eg[4], eb[4];
        #pragma unroll
        for (int q = 0; q < 4; ++q) {
            int i = (int)threadIdx.x + q * NTHR;
            unsigned sidx = s_widx[i];
            float d = depth[sidx];
            float u = (float)(sidx % WW);
            float v = (float)(sidx / WW);
            bool val = (d > 0.1f) && (d < 2.0f) && __builtin_isfinite(d);
            ex[q] = val ? proj_x(u, d) : FINF;
            ey[q] = val ? proj_y(v, d) : FINF;
            ez[q] = val ? d : FINF;
            er[q] = val ? __fdiv_rn(rgb[3u * sidx + 0u], 255.0f) : 0.0f;
            eg[q] = val ? __fdiv_rn(rgb[3u * sidx + 1u], 255.0f) : 0.0f;
            eb[q] = val ? __fdiv_rn(rgb[3u * sidx + 2u], 255.0f) : 0.0f;
        }
        float mn[3], mx[3];
        mn[0] = fminf(fminf(ex[0], ex[1]), fminf(ex[2], ex[3]));
        mx[0] = fmaxf(fmaxf(ex[0], ex[1]), fmaxf(ex[2], ex[3]));
        mn[1] = fminf(fminf(ey[0], ey[1]), fminf(ey[2], ey[3]));
        mx[1] = fmaxf(fmaxf(ey[0], ey[1]), fmaxf(ey[2], ey[3]));
        mn[2] = fminf(fminf(ez[0], ez[1]), fminf(ez[2], ez[3]));
        mx[2] = fmaxf(fmaxf(ez[0], ez[1]), fmaxf(ez[2], ez[3]));
        #pragma unroll
        for (int c = 0; c < 3; ++c) {
            for (int off = 32; off > 0; off >>= 1) {
                mn[c] = fminf(mn[c], __shfl_xor(mn[c], off));
                mx[c] = fmaxf(mx[c], __shfl_xor(mx[c], off));
            }
        }
        __shared__ float s_mn[NWAVE][3], s_mx[NWAVE][3];
        __shared__ float f_mn[3], f_sc[3];
        if (lane == 0) {
            for (int c = 0; c < 3; ++c) { s_mn[wid][c] = mn[c]; s_mx[wid][c] = mx[c]; }
        }
        __syncthreads();
        if (wid == 0) {
            float a[3], b[3];
            for (int c = 0; c < 3; ++c) {
                a[c] = (lane < NWAVE) ? s_mn[lane][c] : FINF;
                b[c] = (lane < NWAVE) ? s_mx[lane][c] : -FINF;
            }
            for (int off = NWAVE / 2; off > 0; off >>= 1) {
                for (int c = 0; c < 3; ++c) {
                    a[c] = fminf(a[c], __shfl_xor(a[c], off));
                    b[c] = fmaxf(b[c], __shfl_xor(b[c], off));
                }
            }
            if (lane == 0) {
                for (int c = 0; c < 3; ++c) {
                    f_mn[c] = a[c];
                    float m = __fsub_rn(b[c], a[c]);   // == max(centered) by monotonicity
                    f_sc[c] = (m < 1e-8f) ? 1.0f : m;
                }
            }
        }
        __syncthreads();
        float MN0 = f_mn[0], MN1 = f_mn[1], MN2 = f_mn[2];
        float SC0 = f_sc[0], SC1 = f_sc[1], SC2 = f_sc[2];
        #pragma unroll
        for (int q = 0; q < 4; ++q) {
            int i = (int)threadIdx.x + q * NTHR;
            out[9 * i + 0] = ex[q];
            out[9 * i + 1] = ey[q];
            out[9 * i + 2] = ez[q];
            out[9 * i + 3] = er[q];
            out[9 * i + 4] = eg[q];
            out[9 * i + 5] = eb[q];
            out[9 * i + 6] = __fdiv_rn(__fsub_rn(ex[q], MN0), SC0);
            out[9 * i + 7] = __fdiv_rn(__fsub_rn(ey[q], MN1), SC1);
            out[9 * i + 8] = __fdiv_rn(__fsub_rn(ez[q], MN2), SC2);
        }
    }
}

extern "C" void kernel_launch(void* const* d_in, const int* in_sizes, int n_in,
                              void* d_out, int out_size, void* d_ws, size_t ws_size,
                              hipStream_t stream) {
    const float* depth = (const float*)d_in[0];
    const float* rgb   = (const float*)d_in[1];
    float* out = (float*)d_out;

    // re-initialize communication slots (deterministic per call / per graph replay)
    zero_ws_kernel<<<dim3((MAXP * NBLK + 255) / 256), dim3(256), 0, stream>>>();

    void* args[] = { (void*)&depth, (void*)&rgb, (void*)&out };
    hipLaunchCooperativeKernel((const void*)fps_kernel, dim3(NBLK), dim3(NTHR),
                               args, 0, stream);
}